// Round 2
// baseline (211.656 us; speedup 1.0000x reference)
//
#include <hip/hip_runtime.h>

// ValleFlashAttention on MI355X (gfx950).
// B=2, N=2048, C=1024, H=16, hd=64. PAD_TAIL=128 (keys >= 1920 masked).
// causal_start read from d_in[2].
//
// Round 6:
//  - Attention: double-buffered K/V staging, single barrier per tile
//    (stage(next) -> compute(cur) -> sync -> flip). Kills the per-tile
//    vmcnt(0) latency drain that held MfmaUtil at 10.7%.
//  - P LDS round-trip ELIMINATED: K rows for QK^T are loaded permuted
//    (row = 32(ni&3) + 8(l16>>2) + 4(ni>>2) + (l16&3)), so each lane's
//    ST values are exactly the PV B-fragment: pb[s] = [ST[s][0..3],
//    ST[s+4][0..3]]. 16 v_cvt_pk_bf16_f32 packs, no Ps buffer, no bank
//    conflicts (was 3.87M conflict cycles).
//  - K staging swizzle f(row)=((row>>3)&3)|((row&1)<<2) keeps the permuted
//    A-reads bank-uniform (8 lanes per 4-bank group = minimum).
//  - Defer-max (T13): skip O-rescale when wave-uniformly mt <= m_+8.
//  - LDS: 2*16K (K) + 2*16K (V) = 64 KB -> 2 blocks/CU.
//  - GEMMs / cvt: unchanged.

typedef unsigned short ushort_t;
typedef short short8 __attribute__((ext_vector_type(8)));
typedef float floatx4 __attribute__((ext_vector_type(4)));
typedef unsigned short ushort4v __attribute__((ext_vector_type(4)));

#define MFMA16(a, b, c) __builtin_amdgcn_mfma_f32_16x16x32_bf16(a, b, c, 0, 0, 0)

__device__ __forceinline__ ushort_t f2bf(float f) {   // RNE
  unsigned int u = __float_as_uint(f);
  u += 0x7fffu + ((u >> 16) & 1u);
  return (ushort_t)(u >> 16);
}

// async global->LDS, 16B per lane; LDS dest must be wave-uniform base + lane*16.
__device__ __forceinline__ void gl_lds16(const ushort_t* g, ushort_t* l) {
  __builtin_amdgcn_global_load_lds(
      (const __attribute__((address_space(1))) void*)g,
      (__attribute__((address_space(3))) void*)l, 16, 0, 0);
}

// ---------------------------------------------------------------- cvt fp32->bf16
__global__ __launch_bounds__(256) void cvt_all_kernel(
    const float* __restrict__ x, const float* __restrict__ wq,
    const float* __restrict__ wp, ushort_t* __restrict__ xb,
    ushort_t* __restrict__ wqb, ushort_t* __restrict__ wpb) {
  int i = (blockIdx.x * 256 + threadIdx.x) * 4;
  const float* s;
  ushort_t* d;
  int off;
  if (i < (4 << 20)) {            // x: 4096*1024
    s = x; d = xb; off = i;
  } else if (i < (7 << 20)) {     // w_qkv: 3072*1024
    s = wq; d = wqb; off = i - (4 << 20);
  } else {                        // w_proj: 1024*1024
    s = wp; d = wpb; off = i - (7 << 20);
  }
  float4 v = *(const float4*)(s + off);
  ushort4v o;
  o.x = f2bf(v.x); o.y = f2bf(v.y); o.z = f2bf(v.z); o.w = f2bf(v.w);
  *(ushort4v*)(d + off) = o;
}

// ---------------------------------------------------------------- GEMM (B^T form)
// C[m][n] = sum_k A[m][k] * Bm[n][k].  128x128 tile, BK=32, 4 waves of 64x64.
template <int EPI>
__global__ __launch_bounds__(256) void gemm_bt(
    const ushort_t* __restrict__ A, const ushort_t* __restrict__ Bm,
    int K, int TN,
    float* __restrict__ outf, float* __restrict__ present,
    ushort_t* __restrict__ q_ws, ushort_t* __restrict__ k_ws,
    ushort_t* __restrict__ vT_ws, const float* __restrict__ b_proj) {
  __shared__ __align__(16) ushort_t As[128 * 32];
  __shared__ __align__(16) ushort_t Bs[128 * 32];
  const int tid = threadIdx.x;
  const int wave = tid >> 6, lane = tid & 63;
  const int quad = lane >> 4, l16 = lane & 15;
  const int wm = wave >> 1, wn = wave & 1;
  const int tm = blockIdx.x / TN, tn = blockIdx.x % TN;

  const int r0 = tid >> 2, c0 = (tid & 3) * 8;
  const int r1 = r0 + 64;
  const ushort_t* a0 = A + (size_t)(tm * 128 + r0) * K + c0;
  const ushort_t* a1 = A + (size_t)(tm * 128 + r1) * K + c0;
  const ushort_t* b0 = Bm + (size_t)(tn * 128 + r0) * K + c0;
  const ushort_t* b1 = Bm + (size_t)(tn * 128 + r1) * K + c0;
  ushort_t* lA0 = As + tid * 8;
  ushort_t* lA1 = As + (tid + 256) * 8;
  ushort_t* lB0 = Bs + tid * 8;
  ushort_t* lB1 = Bs + (tid + 256) * 8;

  floatx4 acc[4][4] = {};

  for (int k0 = 0; k0 < K; k0 += 32) {
    __syncthreads();
    gl_lds16(a0 + k0, lA0);
    gl_lds16(a1 + k0, lA1);
    gl_lds16(b0 + k0, lB0);
    gl_lds16(b1 + k0, lB1);
    __syncthreads();
    short8 af[4], bfr[4];
#pragma unroll
    for (int mi = 0; mi < 4; ++mi)
      af[mi] = *(const short8*)(As + (wm * 64 + mi * 16 + l16) * 32 + quad * 8);
#pragma unroll
    for (int ni = 0; ni < 4; ++ni)
      bfr[ni] = *(const short8*)(Bs + (wn * 64 + ni * 16 + l16) * 32 + quad * 8);
#pragma unroll
    for (int mi = 0; mi < 4; ++mi)
#pragma unroll
      for (int ni = 0; ni < 4; ++ni)
        acc[mi][ni] = MFMA16(af[mi], bfr[ni], acc[mi][ni]);
  }

#pragma unroll
  for (int mi = 0; mi < 4; ++mi) {
#pragma unroll
    for (int ni = 0; ni < 4; ++ni) {
      const int gm0 = tm * 128 + wm * 64 + mi * 16 + quad * 4;
      const int gn = tn * 128 + wn * 64 + ni * 16 + l16;
      if constexpr (EPI == 0) {
        const int b = gm0 >> 11, pos0 = gm0 & 2047;
        const int which = gn >> 10, rem = gn & 1023;
        const int h = rem >> 6, d = rem & 63;
        const size_t hb = (size_t)(b * 16 + h);
        if (which == 0) {
          // Q pre-scaled by hd^-0.5 * log2(e) so softmax runs in exp2 domain.
#pragma unroll
          for (int r = 0; r < 4; ++r)
            q_ws[(hb * 2048 + pos0 + r) * 64 + d] =
                f2bf(acc[mi][ni][r] * 0.1803368867f);
        } else if (which == 1) {
#pragma unroll
          for (int r = 0; r < 4; ++r) {
            size_t pk = (hb * 2048 + pos0 + r) * 64 + d;
            present[pk] = acc[mi][ni][r];
            k_ws[pk] = f2bf(acc[mi][ni][r]);
          }
        } else {
#pragma unroll
          for (int r = 0; r < 4; ++r)
            present[((size_t)((2 + b) * 16 + h) * 2048 + pos0 + r) * 64 + d] =
                acc[mi][ni][r];
          ushort4v pk4;
          pk4.x = f2bf(acc[mi][ni][0]); pk4.y = f2bf(acc[mi][ni][1]);
          pk4.z = f2bf(acc[mi][ni][2]); pk4.w = f2bf(acc[mi][ni][3]);
          *(ushort4v*)(vT_ws + (hb * 64 + d) * 2048 + pos0) = pk4;
        }
      } else {
#pragma unroll
        for (int r = 0; r < 4; ++r)
          outf[(size_t)(gm0 + r) * 1024 + gn] = acc[mi][ni][r] + b_proj[gn];
      }
    }
  }
}

// ---------------------------------------------------------------- flash attention
// grid = 512: gid -> (bh = gid&31, qp = gid>>5). Block processes q-tile pair
// (qp, 31-qp): every block runs ~17 BK=128 k-tiles (equal duration).
// BQ=64 (4 waves x 16 q-rows), BK=128, K/V double-buffered, 1 barrier/tile.
// K rows are loaded permuted so each lane's scores ARE the PV B-fragment.
__global__ __launch_bounds__(256) void attn_kernel(
    const ushort_t* __restrict__ qw, const ushort_t* __restrict__ kw,
    const ushort_t* __restrict__ vtw, ushort_t* __restrict__ attn_out,
    const int* __restrict__ cs_ptr) {
  __shared__ __align__(16) ushort_t Ks[2 * 128 * 64];  // [buf][kpos][d], swizzled
  __shared__ __align__(16) ushort_t Vs[2 * 64 * 128];  // [buf][d][kpos], swizzled
  const int tid = threadIdx.x;
  const int lane = tid & 63;
  const int wave = tid >> 6;
  const int quad = lane >> 4, l16 = lane & 15;

  const int gid = blockIdx.x;
  const int bh = gid & 31, qp = gid >> 5;
  const int b = bh >> 4, h = bh & 15;
  const int cs = cs_ptr[0];
  const size_t headP = (size_t)(b * 16 + h) * 2048 * 64;

  // ---- staging offsets (tile-local; chunk = 8 bf16 = 16B) ----
  // K: LDS chunk (tid&7) of row (s*32 + tid>>3) holds global chunk
  //    (tid&7) ^ f(row), f(row) = ((row>>3)&3) | ((row&1)<<2).
  // V: LDS chunk (tid&15) of row (s*16 + tid>>4) holds global chunk
  //    (tid&15) ^ (row&7).
  int offk[4], offv[4];
#pragma unroll
  for (int s = 0; s < 4; ++s) {
    const int krow = s * 32 + (tid >> 3);
    const int f = ((krow >> 3) & 3) | ((krow & 1) << 2);
    offk[s] = krow * 64 + (((tid & 7) ^ f) << 3);
    const int vrow = s * 16 + (tid >> 4);
    const int vj = (tid & 15) ^ (vrow & 7);
    offv[s] = vrow * 2048 + vj * 8;
  }
  const ushort_t* kbase = kw + headP;
  const ushort_t* vbase = vtw + headP;
  ushort_t* lK = Ks + tid * 8;
  ushort_t* lV = Vs + tid * 8;

  // read-side swizzles
  const int kswz = (l16 >> 2) | ((l16 & 1) << 2);  // = f(permuted row)
  const int vswz = l16 & 7;
  const int lrow = ((l16 >> 2) << 3) + (l16 & 3);  // lane part of permuted K row

  int buf = 0;
  auto stage = [&](int bsel, int kt0) {
    ushort_t* dK = lK + bsel * 8192;
    ushort_t* dV = lV + bsel * 8192;
#pragma unroll
    for (int s = 0; s < 4; ++s)
      gl_lds16(kbase + (size_t)kt0 * 64 + offk[s], dK + s * 2048);
#pragma unroll
    for (int s = 0; s < 4; ++s)
      gl_lds16(vbase + kt0 + offv[s], dV + s * 2048);
  };

  // prologue: stage part-0 tile-0 into buf 0
  stage(0, 0);
  __syncthreads();

#pragma unroll
  for (int part = 0; part < 2; ++part) {
    const int qt = part ? (31 - qp) : qp;
    const int q0 = qt * 64;
    const int wq0 = q0 + wave * 16;

    // Q as B-operand frags (pre-scaled by 0.125*log2e)
    short8 qf[2];
    {
      const int qrow = q0 + wave * 16 + l16;
      qf[0] = *(const short8*)(qw + headP + (size_t)qrow * 64 + quad * 8);
      qf[1] = *(const short8*)(qw + headP + (size_t)qrow * 64 + 32 + quad * 8);
    }

    floatx4 OT[4] = {};          // O^T: row d = di*16+quad*4+r, col q = l16
    float m_ = -1e30f, l_ = 0.f; // per-row state (exp2 domain)

    const int kmax = min(1920, max(q0 + 64, cs));
    const int ntiles = (kmax + 127) >> 7;

    for (int t = 0; t < ntiles; ++t) {
      const int kt0 = t << 7;
      // prefetch next tile (or next part's tile 0) into the other buffer
      if (t + 1 < ntiles)      stage(buf ^ 1, kt0 + 128);
      else if (part == 0)      stage(buf ^ 1, 0);

      const bool active = !(kt0 > wq0 + 15 && kt0 >= cs);
      if (active) {
        const ushort_t* kb = Ks + buf * 8192;

        // S^T = K Q^T with permuted K rows: lane (quad,l16) ST[ni][r] is the
        // score of key k = kt0 + 32(ni&3) + 8quad + 4(ni>>2) + r.
        floatx4 ST[8];
        __builtin_amdgcn_s_setprio(1);
#pragma unroll
        for (int ni = 0; ni < 8; ++ni) {
          const int nrow = ((ni & 3) << 5) + ((ni >> 2) << 2);
          const ushort_t* krow = kb + (nrow + lrow) * 64;
          short8 kf0 = *(const short8*)(krow + ((quad ^ kswz) << 3));
          short8 kf1 = *(const short8*)(krow + (((quad + 4) ^ kswz) << 3));
          floatx4 z = {};
          z = MFMA16(kf0, qf[0], z);
          ST[ni] = MFMA16(kf1, qf[1], z);
        }
        __builtin_amdgcn_s_setprio(0);

        if (kt0 + 127 > wq0) {  // diagonal straddle / tail: elementwise mask
          const int qq = wq0 + l16;
#pragma unroll
          for (int ni = 0; ni < 8; ++ni) {
            const int kb0 = kt0 + ((ni & 3) << 5) + (quad << 3) + ((ni >> 2) << 2);
#pragma unroll
            for (int r = 0; r < 4; ++r) {
              const int k = kb0 + r;
              if (!(k <= qq || k < cs)) ST[ni][r] = -1e30f;
            }
          }
        }

        // softmax over k (exp2 domain): in-lane tree + 2 cross-quad shuffles
        float mt = -1e30f;
#pragma unroll
        for (int ni = 0; ni < 8; ++ni)
#pragma unroll
          for (int r = 0; r < 4; ++r) mt = fmaxf(mt, ST[ni][r]);
        mt = fmaxf(mt, __shfl_xor(mt, 16, 64));
        mt = fmaxf(mt, __shfl_xor(mt, 32, 64));
        // defer-max (T13): skip rescale when the whole wave's maxes are close
        if (!__all(mt <= m_ + 8.0f)) {
          const float mn = fmaxf(m_, mt);
          const float al = exp2f(m_ - mn);
          m_ = mn;
          l_ *= al;
#pragma unroll
          for (int di = 0; di < 4; ++di) OT[di] *= al;
        }
        float rs = 0.f;
#pragma unroll
        for (int ni = 0; ni < 8; ++ni)
#pragma unroll
          for (int r = 0; r < 4; ++r) {
            float pv = exp2f(ST[ni][r] - m_);
            ST[ni][r] = pv;
            rs += pv;
          }
        rs += __shfl_xor(rs, 16, 64);
        rs += __shfl_xor(rs, 32, 64);
        l_ += rs;

        // O^T += V^T P^T : pb[s] is lane-local = [ST[s][0..3], ST[s+4][0..3]]
        const ushort_t* vb = Vs + buf * 8192;
#pragma unroll
        for (int s = 0; s < 4; ++s) {
          int d0, d1, d2, d3;
          asm("v_cvt_pk_bf16_f32 %0, %1, %2" : "=v"(d0) : "v"(ST[s][0]), "v"(ST[s][1]));
          asm("v_cvt_pk_bf16_f32 %0, %1, %2" : "=v"(d1) : "v"(ST[s][2]), "v"(ST[s][3]));
          asm("v_cvt_pk_bf16_f32 %0, %1, %2" : "=v"(d2) : "v"(ST[s + 4][0]), "v"(ST[s + 4][1]));
          asm("v_cvt_pk_bf16_f32 %0, %1, %2" : "=v"(d3) : "v"(ST[s + 4][2]), "v"(ST[s + 4][3]));
          union { int i[4]; short8 v; } u;
          u.i[0] = d0; u.i[1] = d1; u.i[2] = d2; u.i[3] = d3;
          const short8 pb = u.v;
          __builtin_amdgcn_s_setprio(1);
#pragma unroll
          for (int di = 0; di < 4; ++di) {
            const ushort_t* vrow = vb + (di * 16 + l16) * 128;
            short8 vf = *(const short8*)(vrow + ((((s << 2) + quad) ^ vswz) << 3));
            OT[di] = MFMA16(vf, pb, OT[di]);
          }
          __builtin_amdgcn_s_setprio(0);
        }
      }

      __syncthreads();  // staging of next tile complete + all readers done
      buf ^= 1;
    }

    // normalize, pack 4 consecutive d per lane, 8B stores to (B, N, H*hd)
    const float inv = 1.f / l_;
    const int qq = wq0 + l16;
#pragma unroll
    for (int di = 0; di < 4; ++di) {
      ushort4v o4;
      o4.x = f2bf(OT[di][0] * inv);
      o4.y = f2bf(OT[di][1] * inv);
      o4.z = f2bf(OT[di][2] * inv);
      o4.w = f2bf(OT[di][3] * inv);
      *(ushort4v*)(attn_out + ((size_t)(b * 2048 + qq)) * 1024 + h * 64 +
                   di * 16 + quad * 4) = o4;
    }
  }
}

// ---------------------------------------------------------------- launch
extern "C" void kernel_launch(void* const* d_in, const int* in_sizes, int n_in,
                              void* d_out, int out_size, void* d_ws, size_t ws_size,
                              hipStream_t stream) {
  const float* x      = (const float*)d_in[0];
  const int*   cs     = (const int*)d_in[2];
  const float* w_qkv  = (const float*)d_in[3];
  const float* w_proj = (const float*)d_in[4];
  const float* b_proj = (const float*)d_in[5];

  float* out     = (float*)d_out;
  float* present = out + (size_t)2 * 2048 * 1024;

  char* ws = (char*)d_ws;
  ushort_t* xb      = (ushort_t*)(ws);
  ushort_t* wqb     = (ushort_t*)(ws + ((size_t)8  << 20));
  ushort_t* wpb     = (ushort_t*)(ws + ((size_t)14 << 20));
  ushort_t* q_ws    = (ushort_t*)(ws + ((size_t)16 << 20));
  ushort_t* k_ws    = (ushort_t*)(ws + ((size_t)24 << 20));
  ushort_t* vT_ws   = (ushort_t*)(ws + ((size_t)32 << 20));
  ushort_t* attn_ws = (ushort_t*)(ws + ((size_t)40 << 20));

  // 8M elements total, 4/thread -> 8192 blocks exactly.
  cvt_all_kernel<<<8192, 256, 0, stream>>>(x, w_qkv, w_proj, xb, wqb, wpb);

  gemm_bt<0><<<32 * 24, 256, 0, stream>>>(xb, wqb, 1024, 24,
                                          nullptr, present, q_ws, k_ws, vT_ws, nullptr);

  attn_kernel<<<512, 256, 0, stream>>>(q_ws, k_ws, vT_ws, attn_ws, cs);

  gemm_bt<1><<<32 * 8, 256, 0, stream>>>(attn_ws, wpb, 1024, 8,
                                         out, nullptr, nullptr, nullptr, nullptr, b_proj);
}

// Round 3
// 206.618 us; speedup vs baseline: 1.0244x; 1.0244x over previous
//
#include <hip/hip_runtime.h>

// ValleFlashAttention on MI355X (gfx950).
// B=2, N=2048, C=1024, H=16, hd=64. PAD_TAIL=128 (keys >= 1920 masked).
// causal_start read from d_in[2].
//
// Round 7:
//  - Attention occupancy fix: BK=64 double-buffered (LDS 32 KB -> 4 blocks/CU,
//    16 waves/CU = 4 waves/SIMD; was 2). Round-6 counters showed a latency
//    bound (MfmaUtil 10%, Occupancy 17%): softmax dependency chains + vmcnt
//    drain had only 2 waves/SIMD to hide under.
//  - Grid 1024 (one 64-row q-tile per block), longest blocks first
//    (qt = 31 - bid>>5) so scheduler backfill balances causal imbalance.
//    Same-head blocks land on one XCD (bh = bid&31, stride 32 = 0 mod 8).
//  - Tree-reduced max/sum (depth 4, was serial-16 chains).
//  - Permuted-K QK^T (PV B-fragment lane-local, no P LDS round-trip) and
//    K/V staging swizzles carried over from round 6 (verified correct).
//  - GEMMs / cvt: unchanged.

typedef unsigned short ushort_t;
typedef short short8 __attribute__((ext_vector_type(8)));
typedef float floatx4 __attribute__((ext_vector_type(4)));
typedef unsigned short ushort4v __attribute__((ext_vector_type(4)));

#define MFMA16(a, b, c) __builtin_amdgcn_mfma_f32_16x16x32_bf16(a, b, c, 0, 0, 0)

__device__ __forceinline__ ushort_t f2bf(float f) {   // RNE
  unsigned int u = __float_as_uint(f);
  u += 0x7fffu + ((u >> 16) & 1u);
  return (ushort_t)(u >> 16);
}

// async global->LDS, 16B per lane; LDS dest must be wave-uniform base + lane*16.
__device__ __forceinline__ void gl_lds16(const ushort_t* g, ushort_t* l) {
  __builtin_amdgcn_global_load_lds(
      (const __attribute__((address_space(1))) void*)g,
      (__attribute__((address_space(3))) void*)l, 16, 0, 0);
}

// ---------------------------------------------------------------- cvt fp32->bf16
__global__ __launch_bounds__(256) void cvt_all_kernel(
    const float* __restrict__ x, const float* __restrict__ wq,
    const float* __restrict__ wp, ushort_t* __restrict__ xb,
    ushort_t* __restrict__ wqb, ushort_t* __restrict__ wpb) {
  int i = (blockIdx.x * 256 + threadIdx.x) * 4;
  const float* s;
  ushort_t* d;
  int off;
  if (i < (4 << 20)) {            // x: 4096*1024
    s = x; d = xb; off = i;
  } else if (i < (7 << 20)) {     // w_qkv: 3072*1024
    s = wq; d = wqb; off = i - (4 << 20);
  } else {                        // w_proj: 1024*1024
    s = wp; d = wpb; off = i - (7 << 20);
  }
  float4 v = *(const float4*)(s + off);
  ushort4v o;
  o.x = f2bf(v.x); o.y = f2bf(v.y); o.z = f2bf(v.z); o.w = f2bf(v.w);
  *(ushort4v*)(d + off) = o;
}

// ---------------------------------------------------------------- GEMM (B^T form)
// C[m][n] = sum_k A[m][k] * Bm[n][k].  128x128 tile, BK=32, 4 waves of 64x64.
template <int EPI>
__global__ __launch_bounds__(256) void gemm_bt(
    const ushort_t* __restrict__ A, const ushort_t* __restrict__ Bm,
    int K, int TN,
    float* __restrict__ outf, float* __restrict__ present,
    ushort_t* __restrict__ q_ws, ushort_t* __restrict__ k_ws,
    ushort_t* __restrict__ vT_ws, const float* __restrict__ b_proj) {
  __shared__ __align__(16) ushort_t As[128 * 32];
  __shared__ __align__(16) ushort_t Bs[128 * 32];
  const int tid = threadIdx.x;
  const int wave = tid >> 6, lane = tid & 63;
  const int quad = lane >> 4, l16 = lane & 15;
  const int wm = wave >> 1, wn = wave & 1;
  const int tm = blockIdx.x / TN, tn = blockIdx.x % TN;

  const int r0 = tid >> 2, c0 = (tid & 3) * 8;
  const int r1 = r0 + 64;
  const ushort_t* a0 = A + (size_t)(tm * 128 + r0) * K + c0;
  const ushort_t* a1 = A + (size_t)(tm * 128 + r1) * K + c0;
  const ushort_t* b0 = Bm + (size_t)(tn * 128 + r0) * K + c0;
  const ushort_t* b1 = Bm + (size_t)(tn * 128 + r1) * K + c0;
  ushort_t* lA0 = As + tid * 8;
  ushort_t* lA1 = As + (tid + 256) * 8;
  ushort_t* lB0 = Bs + tid * 8;
  ushort_t* lB1 = Bs + (tid + 256) * 8;

  floatx4 acc[4][4] = {};

  for (int k0 = 0; k0 < K; k0 += 32) {
    __syncthreads();
    gl_lds16(a0 + k0, lA0);
    gl_lds16(a1 + k0, lA1);
    gl_lds16(b0 + k0, lB0);
    gl_lds16(b1 + k0, lB1);
    __syncthreads();
    short8 af[4], bfr[4];
#pragma unroll
    for (int mi = 0; mi < 4; ++mi)
      af[mi] = *(const short8*)(As + (wm * 64 + mi * 16 + l16) * 32 + quad * 8);
#pragma unroll
    for (int ni = 0; ni < 4; ++ni)
      bfr[ni] = *(const short8*)(Bs + (wn * 64 + ni * 16 + l16) * 32 + quad * 8);
#pragma unroll
    for (int mi = 0; mi < 4; ++mi)
#pragma unroll
      for (int ni = 0; ni < 4; ++ni)
        acc[mi][ni] = MFMA16(af[mi], bfr[ni], acc[mi][ni]);
  }

#pragma unroll
  for (int mi = 0; mi < 4; ++mi) {
#pragma unroll
    for (int ni = 0; ni < 4; ++ni) {
      const int gm0 = tm * 128 + wm * 64 + mi * 16 + quad * 4;
      const int gn = tn * 128 + wn * 64 + ni * 16 + l16;
      if constexpr (EPI == 0) {
        const int b = gm0 >> 11, pos0 = gm0 & 2047;
        const int which = gn >> 10, rem = gn & 1023;
        const int h = rem >> 6, d = rem & 63;
        const size_t hb = (size_t)(b * 16 + h);
        if (which == 0) {
          // Q pre-scaled by hd^-0.5 * log2(e) so softmax runs in exp2 domain.
#pragma unroll
          for (int r = 0; r < 4; ++r)
            q_ws[(hb * 2048 + pos0 + r) * 64 + d] =
                f2bf(acc[mi][ni][r] * 0.1803368867f);
        } else if (which == 1) {
#pragma unroll
          for (int r = 0; r < 4; ++r) {
            size_t pk = (hb * 2048 + pos0 + r) * 64 + d;
            present[pk] = acc[mi][ni][r];
            k_ws[pk] = f2bf(acc[mi][ni][r]);
          }
        } else {
#pragma unroll
          for (int r = 0; r < 4; ++r)
            present[((size_t)((2 + b) * 16 + h) * 2048 + pos0 + r) * 64 + d] =
                acc[mi][ni][r];
          ushort4v pk4;
          pk4.x = f2bf(acc[mi][ni][0]); pk4.y = f2bf(acc[mi][ni][1]);
          pk4.z = f2bf(acc[mi][ni][2]); pk4.w = f2bf(acc[mi][ni][3]);
          *(ushort4v*)(vT_ws + (hb * 64 + d) * 2048 + pos0) = pk4;
        }
      } else {
#pragma unroll
        for (int r = 0; r < 4; ++r)
          outf[(size_t)(gm0 + r) * 1024 + gn] = acc[mi][ni][r] + b_proj[gn];
      }
    }
  }
}

// ---------------------------------------------------------------- flash attention
// grid = 1024: bid -> bh = bid&31, qt = 31 - (bid>>5) (longest blocks first).
// One 64-row q-tile per block, 4 waves x 16 q-rows. BK=64, K/V double-buffered,
// 1 barrier/tile. LDS 32 KB -> 4 blocks/CU. Permuted K rows make each lane's
// scores exactly the PV B-fragment (no P LDS round-trip).
__global__ __launch_bounds__(256) void attn_kernel(
    const ushort_t* __restrict__ qw, const ushort_t* __restrict__ kw,
    const ushort_t* __restrict__ vtw, ushort_t* __restrict__ attn_out,
    const int* __restrict__ cs_ptr) {
  __shared__ __align__(16) ushort_t Ks[2 * 64 * 64];  // [buf][kpos][d], swizzled
  __shared__ __align__(16) ushort_t Vs[2 * 64 * 64];  // [buf][d][kpos], swizzled
  const int tid = threadIdx.x;
  const int lane = tid & 63;
  const int wave = tid >> 6;
  const int quad = lane >> 4, l16 = lane & 15;

  const int bid = blockIdx.x;
  const int bh = bid & 31;
  const int qt = 31 - (bid >> 5);
  const int b = bh >> 4, h = bh & 15;
  const int cs = cs_ptr[0];
  const size_t headP = (size_t)(b * 16 + h) * 2048 * 64;

  // ---- staging offsets (tile-local; chunk = 8 bf16 = 16B) ----
  // K: LDS chunk (tid&7) of row (s*32 + tid>>3) holds global chunk
  //    (tid&7) ^ f(row), f(row) = ((row>>3)&3) | ((row&1)<<2).
  // V: LDS chunk (tid&7) of row (s*32 + tid>>3) holds global chunk
  //    (tid&7) ^ (row&7).
  int offk[2], offv[2];
#pragma unroll
  for (int s = 0; s < 2; ++s) {
    const int krow = s * 32 + (tid >> 3);
    const int f = ((krow >> 3) & 3) | ((krow & 1) << 2);
    offk[s] = krow * 64 + (((tid & 7) ^ f) << 3);
    const int vrow = s * 32 + (tid >> 3);
    const int vj = (tid & 7) ^ (vrow & 7);
    offv[s] = vrow * 2048 + vj * 8;
  }
  const ushort_t* kbase = kw + headP;
  const ushort_t* vbase = vtw + headP;
  ushort_t* lK = Ks + tid * 8;
  ushort_t* lV = Vs + tid * 8;

  // read-side swizzles
  const int kswz = (l16 >> 2) | ((l16 & 1) << 2);  // = f(permuted row)
  const int vswz = l16 & 7;
  const int lrow = ((l16 >> 2) << 3) + (l16 & 3);  // lane part of permuted K row

  int buf = 0;
  auto stage = [&](int bsel, int kt0) {
    ushort_t* dK = lK + bsel * 4096;
    ushort_t* dV = lV + bsel * 4096;
#pragma unroll
    for (int s = 0; s < 2; ++s)
      gl_lds16(kbase + (size_t)kt0 * 64 + offk[s], dK + s * 2048);
#pragma unroll
    for (int s = 0; s < 2; ++s)
      gl_lds16(vbase + kt0 + offv[s], dV + s * 2048);
  };

  const int q0 = qt * 64;
  const int wq0 = q0 + wave * 16;

  // Q as B-operand frags (pre-scaled by 0.125*log2e)
  short8 qf[2];
  {
    const int qrow = q0 + wave * 16 + l16;
    qf[0] = *(const short8*)(qw + headP + (size_t)qrow * 64 + quad * 8);
    qf[1] = *(const short8*)(qw + headP + (size_t)qrow * 64 + 32 + quad * 8);
  }

  floatx4 OT[4] = {};          // O^T: row d = di*16+quad*4+r, col q = l16
  float m_ = -1e30f, l_ = 0.f; // per-row state (exp2 domain)

  const int kmax = min(1920, max(q0 + 64, cs));
  const int ntiles = (kmax + 63) >> 6;

  // prologue: stage tile 0 into buf 0
  stage(0, 0);
  __syncthreads();

  for (int t = 0; t < ntiles; ++t) {
    const int kt0 = t << 6;
    // prefetch next tile into the other buffer (hidden under compute)
    if (t + 1 < ntiles) stage(buf ^ 1, kt0 + 64);

    const bool active = !(kt0 > wq0 + 15 && kt0 >= cs);
    if (active) {
      const ushort_t* kb = Ks + buf * 4096;

      // S^T = K Q^T with permuted K rows: lane (quad,l16) ST[ni][r] is the
      // score of key k = kt0 + 32(ni&1) + 4(ni>>1) + 8*quad + r.
      floatx4 ST[4];
      __builtin_amdgcn_s_setprio(1);
#pragma unroll
      for (int ni = 0; ni < 4; ++ni) {
        const int nrow = ((ni & 1) << 5) + ((ni >> 1) << 2);
        const ushort_t* krow = kb + (nrow + lrow) * 64;
        short8 kf0 = *(const short8*)(krow + ((quad ^ kswz) << 3));
        short8 kf1 = *(const short8*)(krow + (((quad + 4) ^ kswz) << 3));
        floatx4 z = {};
        z = MFMA16(kf0, qf[0], z);
        ST[ni] = MFMA16(kf1, qf[1], z);
      }
      __builtin_amdgcn_s_setprio(0);

      if (kt0 + 63 > wq0) {  // diagonal straddle / tail: elementwise mask
        const int qq = wq0 + l16;
#pragma unroll
        for (int ni = 0; ni < 4; ++ni) {
          const int kb0 = kt0 + ((ni & 1) << 5) + ((ni >> 1) << 2) + (quad << 3);
#pragma unroll
          for (int r = 0; r < 4; ++r) {
            const int k = kb0 + r;
            if (!(k <= qq || k < cs)) ST[ni][r] = -1e30f;
          }
        }
      }

      // softmax over k (exp2 domain): tree reduce + 2 cross-quad shuffles
      float mt;
      {
        float a0 = fmaxf(fmaxf(ST[0][0], ST[0][1]), fmaxf(ST[0][2], ST[0][3]));
        float a1 = fmaxf(fmaxf(ST[1][0], ST[1][1]), fmaxf(ST[1][2], ST[1][3]));
        float a2 = fmaxf(fmaxf(ST[2][0], ST[2][1]), fmaxf(ST[2][2], ST[2][3]));
        float a3 = fmaxf(fmaxf(ST[3][0], ST[3][1]), fmaxf(ST[3][2], ST[3][3]));
        mt = fmaxf(fmaxf(a0, a1), fmaxf(a2, a3));
      }
      mt = fmaxf(mt, __shfl_xor(mt, 16, 64));
      mt = fmaxf(mt, __shfl_xor(mt, 32, 64));
      // defer-max (T13): skip rescale when the whole wave's maxes are close
      if (!__all(mt <= m_ + 8.0f)) {
        const float mn = fmaxf(m_, mt);
        const float al = exp2f(m_ - mn);
        m_ = mn;
        l_ *= al;
#pragma unroll
        for (int di = 0; di < 4; ++di) OT[di] *= al;
      }
      float sub[4];
#pragma unroll
      for (int ni = 0; ni < 4; ++ni) {
        float p0 = exp2f(ST[ni][0] - m_);
        float p1 = exp2f(ST[ni][1] - m_);
        float p2 = exp2f(ST[ni][2] - m_);
        float p3 = exp2f(ST[ni][3] - m_);
        ST[ni][0] = p0; ST[ni][1] = p1; ST[ni][2] = p2; ST[ni][3] = p3;
        sub[ni] = (p0 + p1) + (p2 + p3);
      }
      float rs = (sub[0] + sub[1]) + (sub[2] + sub[3]);
      rs += __shfl_xor(rs, 16, 64);
      rs += __shfl_xor(rs, 32, 64);
      l_ += rs;

      // O^T += V^T P^T : pb[s] is lane-local = [ST[s][0..3], ST[s+2][0..3]]
      const ushort_t* vb = Vs + buf * 4096;
#pragma unroll
      for (int s = 0; s < 2; ++s) {
        int d0, d1, d2, d3;
        asm("v_cvt_pk_bf16_f32 %0, %1, %2" : "=v"(d0) : "v"(ST[s][0]), "v"(ST[s][1]));
        asm("v_cvt_pk_bf16_f32 %0, %1, %2" : "=v"(d1) : "v"(ST[s][2]), "v"(ST[s][3]));
        asm("v_cvt_pk_bf16_f32 %0, %1, %2" : "=v"(d2) : "v"(ST[s + 2][0]), "v"(ST[s + 2][1]));
        asm("v_cvt_pk_bf16_f32 %0, %1, %2" : "=v"(d3) : "v"(ST[s + 2][2]), "v"(ST[s + 2][3]));
        union { int i[4]; short8 v; } u;
        u.i[0] = d0; u.i[1] = d1; u.i[2] = d2; u.i[3] = d3;
        const short8 pb = u.v;
        __builtin_amdgcn_s_setprio(1);
#pragma unroll
        for (int di = 0; di < 4; ++di) {
          const ushort_t* vrow = vb + (di * 16 + l16) * 64;
          short8 vf = *(const short8*)(vrow + ((((s << 2) + quad) ^ vswz) << 3));
          OT[di] = MFMA16(vf, pb, OT[di]);
        }
        __builtin_amdgcn_s_setprio(0);
      }
    }

    __syncthreads();  // staging of next tile complete + all readers done
    buf ^= 1;
  }

  // normalize, pack 4 consecutive d per lane, 8B stores to (B, N, H*hd)
  const float inv = 1.f / l_;
  const int qq = wq0 + l16;
#pragma unroll
  for (int di = 0; di < 4; ++di) {
    ushort4v o4;
    o4.x = f2bf(OT[di][0] * inv);
    o4.y = f2bf(OT[di][1] * inv);
    o4.z = f2bf(OT[di][2] * inv);
    o4.w = f2bf(OT[di][3] * inv);
    *(ushort4v*)(attn_out + ((size_t)(b * 2048 + qq)) * 1024 + h * 64 +
                 di * 16 + quad * 4) = o4;
  }
}

// ---------------------------------------------------------------- launch
extern "C" void kernel_launch(void* const* d_in, const int* in_sizes, int n_in,
                              void* d_out, int out_size, void* d_ws, size_t ws_size,
                              hipStream_t stream) {
  const float* x      = (const float*)d_in[0];
  const int*   cs     = (const int*)d_in[2];
  const float* w_qkv  = (const float*)d_in[3];
  const float* w_proj = (const float*)d_in[4];
  const float* b_proj = (const float*)d_in[5];

  float* out     = (float*)d_out;
  float* present = out + (size_t)2 * 2048 * 1024;

  char* ws = (char*)d_ws;
  ushort_t* xb      = (ushort_t*)(ws);
  ushort_t* wqb     = (ushort_t*)(ws + ((size_t)8  << 20));
  ushort_t* wpb     = (ushort_t*)(ws + ((size_t)14 << 20));
  ushort_t* q_ws    = (ushort_t*)(ws + ((size_t)16 << 20));
  ushort_t* k_ws    = (ushort_t*)(ws + ((size_t)24 << 20));
  ushort_t* vT_ws   = (ushort_t*)(ws + ((size_t)32 << 20));
  ushort_t* attn_ws = (ushort_t*)(ws + ((size_t)40 << 20));

  // 8M elements total, 4/thread -> 8192 blocks exactly.
  cvt_all_kernel<<<8192, 256, 0, stream>>>(x, w_qkv, w_proj, xb, wqb, wpb);

  gemm_bt<0><<<32 * 24, 256, 0, stream>>>(xb, wqb, 1024, 24,
                                          nullptr, present, q_ws, k_ws, vT_ws, nullptr);

  attn_kernel<<<1024, 256, 0, stream>>>(q_ws, k_ws, vT_ws, attn_ws, cs);

  gemm_bt<1><<<32 * 8, 256, 0, stream>>>(attn_ws, wpb, 1024, 8,
                                         out, nullptr, nullptr, nullptr, nullptr, b_proj);
}